// Round 7
// baseline (266.393 us; speedup 1.0000x reference)
//
#include <hip/hip_runtime.h>
#include <math.h>

#define NB 2
#define NCH 192
#define NH 48
#define NW 48
#define NL 2304
#define NK 4
#define NN 16
#define NR 12
#define ND 44
#define NCHUNK 288
#define CLEN 8                      // NL / NCHUNK
#define LTILE 8
#define NLT (NL / LTILE)            // 288 (== NCHUNK, tile == chunk)

// workspace float sizes
#define SZ_XT    (NB * NCH * NL)                 // 884736
#define SZ_UT0   (NB * NL * NCH)                 // 884736
#define SZ_CB    (NB * NK * NL * NN)             // 294912
#define SZ_CUMS  (NB * NK * NL * NCH)            // 3538944
#define SZ_YBUF  (NB * NK * NL * NCH)            // 3538944
#define SZ_HEND  (NB * NK * NCHUNK * NCH * NN)   // 7077888
#define SZ_A2    (NK * NCH * NN)                 // 12288
#define SZ_XPT   (NK * NCH * ND)                 // 33792

// ---------------- prep: xT + ut0 + A2 + xpw-transpose (one launch)
__global__ __launch_bounds__(256) void k_prep(const float* __restrict__ x,
                                              const float* __restrict__ A_logs,
                                              const float* __restrict__ xpw,
                                              float* __restrict__ xT,
                                              float* __restrict__ ut0,
                                              float* __restrict__ A2buf,
                                              float* __restrict__ xpwT) {
    __shared__ float tile[64 * 193];
    int bid = blockIdx.x;
    if (bid < NB * NCH) {
        // xT[b][c][w*48+h] = x[b][c][h*48+w]
        const float* src = x + (size_t)bid * NL;
        float* dst = xT + (size_t)bid * NL;
        for (int i = threadIdx.x; i < NL; i += 256) {
            int h = i / NW, w = i % NW;
            tile[w * 49 + h] = src[i];
        }
        __syncthreads();
        for (int i = threadIdx.x; i < NL; i += 256) {
            dst[i] = tile[i + i / NH];
        }
    } else if (bid < NB * NCH + NB * 36) {
        // ut0[b][l][c] = x[b][c][l]
        int t = bid - NB * NCH;                // 0..71
        int b = t / 36, lt = t % 36;
        int l0 = lt * 64;
        const float* bx = x + (size_t)b * NCH * NL;
        for (int i = threadIdx.x; i < NCH * 64; i += 256) {
            int c = i >> 6, j = i & 63;        // coalesced read along l
            tile[j * 193 + c] = bx[(size_t)c * NL + l0 + j];
        }
        __syncthreads();
        float* bo = ut0 + (size_t)b * NL * NCH;
        for (int i = threadIdx.x; i < NCH * 64; i += 256) {
            int j = i / NCH, c = i % NCH;      // coalesced write along c
            bo[(size_t)(l0 + j) * NCH + c] = tile[j * 193 + c];
        }
    } else if (bid < NB * NCH + NB * 36 + 12) {
        // A2buf[k][c][n] = -exp(A_logs) * log2(e)
        int t2 = bid - (NB * NCH + NB * 36);   // 0..11
        int i = t2 * 1024 + threadIdx.x;
        for (int q = 0; q < 4; ++q, i += 256)
            A2buf[i] = -expf(A_logs[i]) * 1.44269504f;
    } else {
        // xpwT[k][c][d] = xpw[k][d][c]   (tiny: 33792 floats)
        int k = bid - (NB * NCH + NB * 36 + 12);   // 0..3
        for (int i = threadIdx.x; i < NCH * ND; i += 256) {
            int c = i / ND, d = i % ND;
            xpwT[((size_t)k * NCH + c) * ND + d] =
                xpw[((size_t)k * ND + d) * NCH + c];
        }
    }
}

__device__ __forceinline__ int u_row(int k, int l) {
    int pos = (k >= 2) ? (NL - 1 - l) : l;
    if (k & 1) pos = (pos % 48) * 48 + (pos / 48);
    return pos;
}

// ---- fused proj + delta + chunk-local scan emitting y_local.
// CLEN=8: 2304 blocks (9/CU -> ~84% occ bound vs 42% at CLEN=16).
// 4 cc-phases of 48 keep LDS ~14 KB. 4d x 4l thread tiles, 8-way cc split.
#define WLP 44
#define XSP 12
#define CPH 48
__global__ __launch_bounds__(192) void k_projscan(const float* __restrict__ x,
                                                  const float* __restrict__ xT,
                                                  const float* __restrict__ xpwT,
                                                  const float* __restrict__ dtw,
                                                  const float* __restrict__ dt_bias,
                                                  const float* __restrict__ A2buf,
                                                  const float* __restrict__ Ds,
                                                  const float* __restrict__ ut0,
                                                  float* __restrict__ Cbuf,
                                                  float* __restrict__ cumS,
                                                  float* __restrict__ ybuf,
                                                  float* __restrict__ Hend) {
    int bid = blockIdx.x;                      // 8 * 288
    int bk = bid / NLT;
    int chk = bid % NLT;
    int lt0 = chk * LTILE;
    int b = bk >> 2, k = bk & 3;
    int tid = threadIdx.x;
    __shared__ float SMEM[3168];               // WL[48*44]+XS[48*12] / PACC union
    __shared__ float DT[LTILE * NR];
    __shared__ float BL[LTILE * NN];
    __shared__ float CL[LTILE * NN];
    float* WL = SMEM;                          // [cc][44]   8448 B
    float* XS = SMEM + CPH * WLP;              // [cc][12]   2304 B
    float* PACC = SMEM;                        // [l8][d44][9] 12672 B (aliases)
    const float* bx = ((k & 1) ? xT : x) + (size_t)b * NCH * NL;
    bool rev = (k >= 2);
    int gbase = rev ? (NL - LTILE - lt0) : lt0;

    // proj mapping: dg (d-group of 4) x lg (l-group of 4) x sp (8-way cc split)
    int dg = tid % 11;                         // 0..10
    int rr = tid / 11;                         // 0..17
    int lg = rr & 1;                           // 0..1
    int sp = rr >> 1;                          // 0..7 (tid<176)
    float acc[4][4] = {};
    for (int ph = 0; ph < 4; ++ph) {
        int c0 = ph * CPH;
        __syncthreads();
        for (int i = tid; i < CPH * 11; i += 192) {
            int cc = i / 11, ds = i % 11;      // coalesced b128 along ds
            float4 v = *(const float4*)(xpwT + ((size_t)k * NCH + c0 + cc) * ND + ds * 4);
            *(float4*)&WL[cc * WLP + ds * 4] = v;
        }
        for (int i = tid; i < CPH * 2; i += 192) {
            int cc = i >> 1, q4 = i & 1;       // float4 per thread (8 l = 2 quads)
            float4 v = *(const float4*)(bx + (size_t)(c0 + cc) * NL + gbase + q4 * 4);
            if (!rev) {
                *(float4*)&XS[cc * XSP + q4 * 4] = v;
            } else {
                *(float4*)&XS[cc * XSP + (1 - q4) * 4] =
                    make_float4(v.w, v.z, v.y, v.x);
            }
        }
        __syncthreads();
        if (tid < 176) {
#pragma unroll
            for (int ii = 0; ii < 6; ++ii) {
                int cc = ii * 8 + sp;
                float4 wv = *(const float4*)&WL[cc * WLP + dg * 4];
                float4 xv = *(const float4*)&XS[cc * XSP + lg * 4];
                float xa[4] = {xv.x, xv.y, xv.z, xv.w};
                float wa[4] = {wv.x, wv.y, wv.z, wv.w};
#pragma unroll
                for (int li = 0; li < 4; ++li)
#pragma unroll
                    for (int dd = 0; dd < 4; ++dd)
                        acc[li][dd] = fmaf(xa[li], wa[dd], acc[li][dd]);
            }
        }
    }
    __syncthreads();                           // WL/XS dead -> PACC
    if (tid < 176) {
#pragma unroll
        for (int li = 0; li < 4; ++li)
#pragma unroll
            for (int dd = 0; dd < 4; ++dd) {
                int l = lg * 4 + li, d = dg * 4 + dd;
                PACC[(l * ND + d) * 9 + sp] = acc[li][dd];
            }
    }
    __syncthreads();
    if (tid < 176) {
#pragma unroll
        for (int rep = 0; rep < 2; ++rep) {
            int idx = tid + rep * 176;         // 0..351 = (l, dt)
            int l = idx / ND, dt = idx % ND;
            const float* pp = &PACC[(l * ND + dt) * 9];
            float v = ((pp[0] + pp[1]) + (pp[2] + pp[3]))
                    + ((pp[4] + pp[5]) + (pp[6] + pp[7]));
            if (dt < NR) {
                DT[l * NR + dt] = v;
            } else if (dt < NR + NN) {
                BL[l * NN + (dt - NR)] = v;
            } else {
                CL[l * NN + (dt - NR - NN)] = v;
                Cbuf[((size_t)bk * NL + lt0 + l) * NN + (dt - NR - NN)] = v;
            }
        }
    }
    __syncthreads();
    // ------- tail: thread c does delta+softplus then 8-step local scan
    int c = tid;
    float A2[NN];
    {
        const float4* ap = (const float4*)(A2buf + ((size_t)(k * NCH + c)) * NN);
        float4 a0 = ap[0], a1 = ap[1], a2 = ap[2], a3 = ap[3];
        A2[0]=a0.x; A2[1]=a0.y; A2[2]=a0.z; A2[3]=a0.w;
        A2[4]=a1.x; A2[5]=a1.y; A2[6]=a1.z; A2[7]=a1.w;
        A2[8]=a2.x; A2[9]=a2.y; A2[10]=a2.z; A2[11]=a2.w;
        A2[12]=a3.x; A2[13]=a3.y; A2[14]=a3.z; A2[15]=a3.w;
    }
    const float4* wp = (const float4*)(dtw + ((size_t)k * NCH + c) * NR);
    float4 w0 = wp[0], w1 = wp[1], w2 = wp[2];
    float bias = dt_bias[k * NCH + c];
    float dval = Ds[k * NCH + c];
    const float* up = ut0 + (size_t)b * NL * NCH + c;
    float* csp = cumS + (size_t)bk * NL * NCH + c;
    float sp_[CLEN], uvv[CLEN];
    float S = 0.0f;
#pragma unroll
    for (int i = 0; i < CLEN; ++i) {
        int l = lt0 + i;
        float4 a0 = *(const float4*)&DT[i * NR + 0];
        float4 a1 = *(const float4*)&DT[i * NR + 4];
        float4 a2 = *(const float4*)&DT[i * NR + 8];
        float p0 = fmaf(w0.x, a0.x, fmaf(w0.y, a0.y, bias));
        float p1 = fmaf(w0.z, a0.z, w0.w * a0.w);
        float p2 = fmaf(w1.x, a1.x, fmaf(w1.y, a1.y, w1.z * a1.z));
        float p3 = fmaf(w1.w, a1.w, fmaf(w2.x, a2.x, w2.y * a2.y));
        float p4 = fmaf(w2.z, a2.z, w2.w * a2.w);
        float acc2 = (p0 + p1) + (p2 + p3) + p4;
        float s = fmaxf(acc2, 0.0f) + __logf(1.0f + __expf(-fabsf(acc2)));
        sp_[i] = s;
        S += s;
        csp[(size_t)l * NCH] = S;
        uvv[i] = up[(size_t)u_row(k, l) * NCH];
    }
    float h[NN];
#pragma unroll
    for (int n = 0; n < NN; ++n) h[n] = 0.0f;
    float* yp = ybuf + (size_t)bk * NL * NCH + c;
#pragma unroll
    for (int i = 0; i < CLEN; ++i) {
        float du = sp_[i] * uvv[i];
        const float4* br = (const float4*)&BL[i * NN];
        float4 b0 = br[0], b1 = br[1], b2 = br[2], b3 = br[3];
        float Bv[16] = {b0.x, b0.y, b0.z, b0.w, b1.x, b1.y, b1.z, b1.w,
                        b2.x, b2.y, b2.z, b2.w, b3.x, b3.y, b3.z, b3.w};
        const float4* cr = (const float4*)&CL[i * NN];
        float4 c0 = cr[0], c1 = cr[1], c2 = cr[2], c3 = cr[3];
        float Cv[16] = {c0.x, c0.y, c0.z, c0.w, c1.x, c1.y, c1.z, c1.w,
                        c2.x, c2.y, c2.z, c2.w, c3.x, c3.y, c3.z, c3.w};
        float y = 0.0f;
#pragma unroll
        for (int n = 0; n < NN; ++n) {
            float dA = exp2f(sp_[i] * A2[n]);
            h[n] = fmaf(dA, h[n], du * Bv[n]);
            y = fmaf(h[n], Cv[n], y);
        }
        y = fmaf(dval, uvv[i], y);
        yp[(size_t)(lt0 + i) * NCH] = y;
    }
    size_t ob = (((size_t)bk * NCHUNK + chk) * NCH + c) * NN;
#pragma unroll
    for (int q = 0; q < 4; ++q)
        *(float4*)&Hend[ob + q * 4] =
            make_float4(h[q*4], h[q*4+1], h[q*4+2], h[q*4+3]);
}

// ------------- scan pass 2: chunk-PAIR combine + 144-wide Hillis-Steele.
// Thread j owns chunks 2j, 2j+1 (combined), n-quad split, b128-packed rows.
#define S2ROW 12
__global__ __launch_bounds__(144) void k_s2(const float* __restrict__ cumS,
                                            const float* __restrict__ A2buf,
                                            float* __restrict__ Hend) {
    __shared__ float SC[144 * S2ROW];          // 6.9 KB
    int bid = blockIdx.x;                      // 8 * 192 * 4
    int bk = bid / (NCH * 4);
    int r = bid % (NCH * 4);
    int c = r >> 2, nq = r & 3;
    int k = bk & 3;
    int j = threadIdx.x;                       // pair index, all 144 active
    float4 a = *(const float4*)(A2buf + ((size_t)(k * NCH + c)) * NN + nq * 4);
    float A2[4] = {a.x, a.y, a.z, a.w};
    size_t csb = (size_t)bk * NL * NCH + c;
    float Sv0 = cumS[csb + (size_t)((2 * j) * CLEN + CLEN - 1) * NCH];
    float Sv1 = cumS[csb + (size_t)((2 * j + 1) * CLEN + CLEN - 1) * NCH];
    size_t eb0 = (((size_t)bk * NCHUNK + 2 * j) * NCH + c) * NN + nq * 4;
    size_t eb1 = eb0 + (size_t)NCH * NN;
    float4 e0v = *(const float4*)(Hend + eb0);
    float4 e1v = *(const float4*)(Hend + eb1);
    float E0[4] = {e0v.x, e0v.y, e0v.z, e0v.w};
    float E1[4] = {e1v.x, e1v.y, e1v.z, e1v.w};
    float P0[4], P[4], E[4];
#pragma unroll
    for (int n = 0; n < 4; ++n) {
        P0[n] = exp2f(Sv0 * A2[n]);
        float P1 = exp2f(Sv1 * A2[n]);
        P[n] = P0[n] * P1;                     // pair decay
        E[n] = fmaf(P1, E0[n], E1[n]);         // pair emission
    }
    *(float4*)&SC[j * S2ROW + 0] = make_float4(P[0], P[1], P[2], P[3]);
    *(float4*)&SC[j * S2ROW + 4] = make_float4(E[0], E[1], E[2], E[3]);
    for (int s = 1; s < 144; s <<= 1) {        // 8 steps
        __syncthreads();
        float4 pe, ee;
        bool act = (j >= s);
        if (act) {
            pe = *(const float4*)&SC[(j - s) * S2ROW + 0];
            ee = *(const float4*)&SC[(j - s) * S2ROW + 4];
        }
        __syncthreads();
        if (act) {
            float pea[4] = {pe.x, pe.y, pe.z, pe.w};
            float eea[4] = {ee.x, ee.y, ee.z, ee.w};
#pragma unroll
            for (int n = 0; n < 4; ++n) {
                E[n] = fmaf(P[n], eea[n], E[n]);
                P[n] = P[n] * pea[n];
            }
            *(float4*)&SC[j * S2ROW + 0] = make_float4(P[0], P[1], P[2], P[3]);
            *(float4*)&SC[j * S2ROW + 4] = make_float4(E[0], E[1], E[2], E[3]);
        }
    }
    __syncthreads();
    float pref[4] = {0.f, 0.f, 0.f, 0.f};
    if (j > 0) {
        float4 pv = *(const float4*)&SC[(j - 1) * S2ROW + 4];
        pref[0] = pv.x; pref[1] = pv.y; pref[2] = pv.z; pref[3] = pv.w;
    }
    *(float4*)&Hend[eb0] = make_float4(pref[0], pref[1], pref[2], pref[3]);
    float o1[4];
#pragma unroll
    for (int n = 0; n < 4; ++n) o1[n] = fmaf(P0[n], pref[n], E0[n]);
    *(float4*)&Hend[eb1] = make_float4(o1[0], o1[1], o1[2], o1[3]);
}

// -------- fix: y += C · (exp2(cumS·A2) ∘ h_in) — one block per 8-l chunk
__global__ __launch_bounds__(192) void k_fix(const float* __restrict__ Cbuf,
                                             const float* __restrict__ cumS,
                                             const float* __restrict__ Hin,
                                             const float* __restrict__ A2buf,
                                             float* __restrict__ ybuf) {
    int bid = blockIdx.x;                      // 8 * 288
    int bk = bid / NCHUNK;
    int chk = bid % NCHUNK;
    int lt0 = chk * CLEN;
    int k = bk & 3;
    int c = threadIdx.x;
    float A2[NN];
    {
        const float4* ap = (const float4*)(A2buf + ((size_t)(k * NCH + c)) * NN);
        float4 a0 = ap[0], a1 = ap[1], a2 = ap[2], a3 = ap[3];
        A2[0]=a0.x; A2[1]=a0.y; A2[2]=a0.z; A2[3]=a0.w;
        A2[4]=a1.x; A2[5]=a1.y; A2[6]=a1.z; A2[7]=a1.w;
        A2[8]=a2.x; A2[9]=a2.y; A2[10]=a2.z; A2[11]=a2.w;
        A2[12]=a3.x; A2[13]=a3.y; A2[14]=a3.z; A2[15]=a3.w;
    }
    float hin[NN];
    {
        size_t ob = (((size_t)bk * NCHUNK + chk) * NCH + c) * NN;
        const float4* hp = (const float4*)(Hin + ob);
        float4 h0 = hp[0], h1 = hp[1], h2 = hp[2], h3 = hp[3];
        float t[16] = {h0.x, h0.y, h0.z, h0.w, h1.x, h1.y, h1.z, h1.w,
                       h2.x, h2.y, h2.z, h2.w, h3.x, h3.y, h3.z, h3.w};
#pragma unroll
        for (int n = 0; n < NN; ++n) hin[n] = t[n];
    }
    const float* csp = cumS + (size_t)bk * NL * NCH + c;
    float* yp = ybuf + (size_t)bk * NL * NCH + c;
#pragma unroll
    for (int i = 0; i < CLEN; ++i) {
        int l = lt0 + i;
        float cs = csp[(size_t)l * NCH];
        const float4* cr = (const float4*)(Cbuf + ((size_t)bk * NL + l) * NN);
        float4 c0 = cr[0], c1 = cr[1], c2 = cr[2], c3 = cr[3];
        float Cv[16] = {c0.x, c0.y, c0.z, c0.w, c1.x, c1.y, c1.z, c1.w,
                        c2.x, c2.y, c2.z, c2.w, c3.x, c3.y, c3.z, c3.w};
        float corr = 0.0f;
#pragma unroll
        for (int n = 0; n < NN; ++n) {
            float e = exp2f(cs * A2[n]);
            corr = fmaf(Cv[n] * hin[n], e, corr);
        }
        yp[(size_t)l * NCH] += corr;
    }
}

// ------------------------------------------- cross-merge, split ×4 over c
__global__ __launch_bounds__(256) void k_merge(const float* __restrict__ ybuf,
                                               float* __restrict__ out) {
    int bid = blockIdx.x;                // NB * NH * 4 = 384
    int b = bid / (NH * 4);
    int r = bid % (NH * 4);
    int hh = r >> 2, cq = r & 3;
    int cbase = cq * 48;
    __shared__ float tile[NW * 49];
    const float* Y0 = ybuf + (size_t)(b * NK + 0) * NL * NCH;
    const float* Y1 = ybuf + (size_t)(b * NK + 1) * NL * NCH;
    const float* Y2 = ybuf + (size_t)(b * NK + 2) * NL * NCH;
    const float* Y3 = ybuf + (size_t)(b * NK + 3) * NL * NCH;
    for (int i = threadIdx.x; i < NW * 48; i += 256) {
        int w = i / 48, cs = i % 48;
        int c = cbase + cs;
        int hw = hh * NW + w;
        int wh = w * NH + hh;
        float v = Y0[(size_t)hw * NCH + c]
                + Y2[(size_t)(NL - 1 - hw) * NCH + c]
                + Y1[(size_t)wh * NCH + c]
                + Y3[(size_t)(NL - 1 - wh) * NCH + c];
        tile[w * 49 + cs] = v;
    }
    __syncthreads();
    for (int i = threadIdx.x; i < NW * 48; i += 256) {
        int cs = i / NW, w = i % NW;
        out[((size_t)(b * NCH + cbase + cs)) * NL + hh * NW + w] = tile[w * 49 + cs];
    }
}

extern "C" void kernel_launch(void* const* d_in, const int* in_sizes, int n_in,
                              void* d_out, int out_size, void* d_ws, size_t ws_size,
                              hipStream_t stream) {
    const float* x      = (const float*)d_in[0];
    const float* xpw    = (const float*)d_in[1];
    const float* dtw    = (const float*)d_in[2];
    const float* A_logs = (const float*)d_in[3];
    const float* Ds     = (const float*)d_in[4];
    const float* dtb    = (const float*)d_in[5];
    float* out = (float*)d_out;

    float* ws = (float*)d_ws;
    float* xT    = ws;
    float* ut0   = xT + SZ_XT;
    float* Cbuf  = ut0 + SZ_UT0;
    float* cumS  = Cbuf + SZ_CB;
    float* ybuf  = cumS + SZ_CUMS;
    float* Hend  = ybuf + SZ_YBUF;   // after k_s2 holds Hin (in-place)
    float* A2buf = Hend + SZ_HEND;
    float* xpwT  = A2buf + SZ_A2;

    k_prep<<<NB * NCH + NB * 36 + 12 + NK, 256, 0, stream>>>(x, A_logs, xpw,
                                                             xT, ut0, A2buf, xpwT);
    k_projscan<<<NB * NK * NLT, 192, 0, stream>>>(x, xT, xpwT, dtw, dtb, A2buf,
                                                  Ds, ut0, Cbuf, cumS, ybuf, Hend);
    k_s2<<<NB * NK * NCH * 4, 144, 0, stream>>>(cumS, A2buf, Hend);
    k_fix<<<NB * NK * NCHUNK, 192, 0, stream>>>(Cbuf, cumS, Hend, A2buf, ybuf);
    k_merge<<<NB * NH * 4, 256, 0, stream>>>(ybuf, out);
}

// Round 8
// 156.025 us; speedup vs baseline: 1.7074x; 1.7074x over previous
//
#include <hip/hip_runtime.h>
#include <math.h>

#define NB 2
#define NCH 192
#define NH 48
#define NW 48
#define NL 2304
#define NK 4
#define NN 16
#define NR 12
#define ND 44
#define NCHUNK 144
#define CLEN 16                     // NL / NCHUNK
#define LTILE 16
#define NLT (NL / LTILE)            // 144 (== NCHUNK, tile == chunk)

// workspace float sizes
#define SZ_XT    (NB * NCH * NL)                 // 884736
#define SZ_UT0   (NB * NL * NCH)                 // 884736
#define SZ_CB    (NB * NK * NL * NN)             // 294912
#define SZ_CUMS  (NB * NK * NL * NCH)            // 3538944
#define SZ_YBUF  (NB * NK * NL * NCH)            // 3538944
#define SZ_HEND  (NB * NK * NCHUNK * NCH * NN)   // 3538944
#define SZ_A2    (NK * NCH * NN)                 // 12288
#define SZ_XPT   (NK * NCH * ND)                 // 33792

// ---------------- prep: xT + ut0 + A2 + xpw-transpose (one launch)
__global__ __launch_bounds__(256) void k_prep(const float* __restrict__ x,
                                              const float* __restrict__ A_logs,
                                              const float* __restrict__ xpw,
                                              float* __restrict__ xT,
                                              float* __restrict__ ut0,
                                              float* __restrict__ A2buf,
                                              float* __restrict__ xpwT) {
    __shared__ float tile[64 * 193];
    int bid = blockIdx.x;
    if (bid < NB * NCH) {
        // xT[b][c][w*48+h] = x[b][c][h*48+w]
        const float* src = x + (size_t)bid * NL;
        float* dst = xT + (size_t)bid * NL;
        for (int i = threadIdx.x; i < NL; i += 256) {
            int h = i / NW, w = i % NW;
            tile[w * 49 + h] = src[i];
        }
        __syncthreads();
        for (int i = threadIdx.x; i < NL; i += 256) {
            dst[i] = tile[i + i / NH];
        }
    } else if (bid < NB * NCH + NB * 36) {
        // ut0[b][l][c] = x[b][c][l]
        int t = bid - NB * NCH;                // 0..71
        int b = t / 36, lt = t % 36;
        int l0 = lt * 64;
        const float* bx = x + (size_t)b * NCH * NL;
        for (int i = threadIdx.x; i < NCH * 64; i += 256) {
            int c = i >> 6, j = i & 63;        // coalesced read along l
            tile[j * 193 + c] = bx[(size_t)c * NL + l0 + j];
        }
        __syncthreads();
        float* bo = ut0 + (size_t)b * NL * NCH;
        for (int i = threadIdx.x; i < NCH * 64; i += 256) {
            int j = i / NCH, c = i % NCH;      // coalesced write along c
            bo[(size_t)(l0 + j) * NCH + c] = tile[j * 193 + c];
        }
    } else if (bid < NB * NCH + NB * 36 + 12) {
        // A2buf[k][c][n] = -exp(A_logs) * log2(e)
        int t2 = bid - (NB * NCH + NB * 36);   // 0..11
        int i = t2 * 1024 + threadIdx.x;
        for (int q = 0; q < 4; ++q, i += 256)
            A2buf[i] = -expf(A_logs[i]) * 1.44269504f;
    } else {
        // xpwT[k][c][d] = xpw[k][d][c]   (tiny: 33792 floats)
        int k = bid - (NB * NCH + NB * 36 + 12);   // 0..3
        for (int i = threadIdx.x; i < NCH * ND; i += 256) {
            int c = i / ND, d = i % ND;
            xpwT[((size_t)k * NCH + c) * ND + d] =
                xpw[((size_t)k * ND + d) * NCH + c];
        }
    }
}

__device__ __forceinline__ int u_row(int k, int l) {
    int pos = (k >= 2) ? (NL - 1 - l) : l;
    if (k & 1) pos = (pos % 48) * 48 + (pos / 48);
    return pos;
}

// ---- fused proj + delta + chunk-local scan emitting y_local.
// 4d x 4l thread tiles; WL staged from pre-transposed xpwT with b128
// coalesced loads + b128 LDS writes; plain [cc][44] layout.
#define WLP 44
#define XSP 20
#define PACCP 5
__global__ __launch_bounds__(192) void k_projscan(const float* __restrict__ x,
                                                  const float* __restrict__ xT,
                                                  const float* __restrict__ xpwT,
                                                  const float* __restrict__ dtw,
                                                  const float* __restrict__ dt_bias,
                                                  const float* __restrict__ A2buf,
                                                  const float* __restrict__ Ds,
                                                  const float* __restrict__ ut0,
                                                  float* __restrict__ Cbuf,
                                                  float* __restrict__ cumS,
                                                  float* __restrict__ ybuf,
                                                  float* __restrict__ Hend) {
    int bid = blockIdx.x;                      // 8 * 144
    int bk = bid / NLT;
    int chk = bid % NLT;
    int lt0 = chk * LTILE;
    int b = bk >> 2, k = bk & 3;
    int tid = threadIdx.x;
    __shared__ float WL[96 * WLP];             // [cc][d]           16.9 KB
    __shared__ float XS[96 * XSP];             // [cc][l] pad 20     7.7 KB
    __shared__ float DT[LTILE * NR];           // dts
    __shared__ float BL[LTILE * NN];           // B
    __shared__ float CL[LTILE * NN];           // C
    float* PACC = WL;                          // alias: [l16][d44][sp4] pad 5
    const float* bx = ((k & 1) ? xT : x) + (size_t)b * NCH * NL;
    bool rev = (k >= 2);
    int gbase = rev ? (NL - LTILE - lt0) : lt0;

    // thread mapping for proj: dg (d-group of 4) x lg (l-group of 4) x sp (cc-split)
    int dg = tid % 11;                         // 0..10
    int rr = tid / 11;                         // 0..16
    int lg = rr & 3;                           // 0..3
    int sp = rr >> 2;                          // 0..3
    float acc[4][4] = {};
    for (int ph = 0; ph < 2; ++ph) {
        int c0 = ph * 96;
        __syncthreads();
        for (int i = tid; i < 96 * 11; i += 192) {
            int cc = i / 11, ds = i % 11;      // coalesced b128 along ds
            float4 v = *(const float4*)(xpwT + ((size_t)k * NCH + c0 + cc) * ND + ds * 4);
            *(float4*)&WL[cc * WLP + ds * 4] = v;
        }
        for (int i = tid; i < 96 * 4; i += 192) {
            int cc = i >> 2, q4 = i & 3;       // float4 per thread
            float4 v = *(const float4*)(bx + (size_t)(c0 + cc) * NL + gbase + q4 * 4);
            if (!rev) {
                *(float4*)&XS[cc * XSP + q4 * 4] = v;
            } else {
                *(float4*)&XS[cc * XSP + (3 - q4) * 4] =
                    make_float4(v.w, v.z, v.y, v.x);
            }
        }
        __syncthreads();
        if (tid < 176) {
#pragma unroll 8
            for (int ii = 0; ii < 24; ++ii) {
                int cc = 4 * ii + sp;
                float4 wv = *(const float4*)&WL[cc * WLP + dg * 4];
                float4 xv = *(const float4*)&XS[cc * XSP + lg * 4];
                float xa[4] = {xv.x, xv.y, xv.z, xv.w};
                float wa[4] = {wv.x, wv.y, wv.z, wv.w};
#pragma unroll
                for (int li = 0; li < 4; ++li)
#pragma unroll
                    for (int dd = 0; dd < 4; ++dd)
                        acc[li][dd] = fmaf(xa[li], wa[dd], acc[li][dd]);
            }
        }
    }
    __syncthreads();                           // WL dead -> PACC
    if (tid < 176) {
#pragma unroll
        for (int li = 0; li < 4; ++li)
#pragma unroll
            for (int dd = 0; dd < 4; ++dd) {
                int l = lg * 4 + li, d = dg * 4 + dd;
                PACC[(l * ND + d) * PACCP + sp] = acc[li][dd];
            }
    }
    __syncthreads();
    if (tid < 176) {
        int lt = tid / ND, dt = tid % ND;
#pragma unroll
        for (int li = 0; li < 4; ++li) {
            int l = lt * 4 + li;               // within tile
            const float* pp = &PACC[(l * ND + dt) * PACCP];
            float v = (pp[0] + pp[1]) + (pp[2] + pp[3]);
            if (dt < NR) {
                DT[l * NR + dt] = v;
            } else if (dt < NR + NN) {
                BL[l * NN + (dt - NR)] = v;
            } else {
                CL[l * NN + (dt - NR - NN)] = v;
                Cbuf[((size_t)bk * NL + lt0 + l) * NN + (dt - NR - NN)] = v;
            }
        }
    }
    __syncthreads();
    // ------- tail: thread c does delta+softplus (ILP phase) then local scan
    int c = tid;
    float A2[NN];
    {
        const float4* ap = (const float4*)(A2buf + ((size_t)(k * NCH + c)) * NN);
        float4 a0 = ap[0], a1 = ap[1], a2 = ap[2], a3 = ap[3];
        A2[0]=a0.x; A2[1]=a0.y; A2[2]=a0.z; A2[3]=a0.w;
        A2[4]=a1.x; A2[5]=a1.y; A2[6]=a1.z; A2[7]=a1.w;
        A2[8]=a2.x; A2[9]=a2.y; A2[10]=a2.z; A2[11]=a2.w;
        A2[12]=a3.x; A2[13]=a3.y; A2[14]=a3.z; A2[15]=a3.w;
    }
    const float4* wp = (const float4*)(dtw + ((size_t)k * NCH + c) * NR);
    float4 w0 = wp[0], w1 = wp[1], w2 = wp[2];
    float bias = dt_bias[k * NCH + c];
    float dval = Ds[k * NCH + c];
    const float* up = ut0 + (size_t)b * NL * NCH + c;
    float* csp = cumS + (size_t)bk * NL * NCH + c;
    float sp_[CLEN], uvv[CLEN];
    float S = 0.0f;
#pragma unroll
    for (int i = 0; i < CLEN; ++i) {
        int l = lt0 + i;
        float4 a0 = *(const float4*)&DT[i * NR + 0];
        float4 a1 = *(const float4*)&DT[i * NR + 4];
        float4 a2 = *(const float4*)&DT[i * NR + 8];
        float p0 = fmaf(w0.x, a0.x, fmaf(w0.y, a0.y, bias));
        float p1 = fmaf(w0.z, a0.z, w0.w * a0.w);
        float p2 = fmaf(w1.x, a1.x, fmaf(w1.y, a1.y, w1.z * a1.z));
        float p3 = fmaf(w1.w, a1.w, fmaf(w2.x, a2.x, w2.y * a2.y));
        float p4 = fmaf(w2.z, a2.z, w2.w * a2.w);
        float acc2 = (p0 + p1) + (p2 + p3) + p4;
        float s = fmaxf(acc2, 0.0f) + __logf(1.0f + __expf(-fabsf(acc2)));
        sp_[i] = s;
        S += s;
        csp[(size_t)l * NCH] = S;
        uvv[i] = up[(size_t)u_row(k, l) * NCH];
    }
    float h[NN];
#pragma unroll
    for (int n = 0; n < NN; ++n) h[n] = 0.0f;
    float* yp = ybuf + (size_t)bk * NL * NCH + c;
#pragma unroll 4
    for (int i = 0; i < CLEN; ++i) {
        float du = sp_[i] * uvv[i];
        const float4* br = (const float4*)&BL[i * NN];
        float4 b0 = br[0], b1 = br[1], b2 = br[2], b3 = br[3];
        float Bv[16] = {b0.x, b0.y, b0.z, b0.w, b1.x, b1.y, b1.z, b1.w,
                        b2.x, b2.y, b2.z, b2.w, b3.x, b3.y, b3.z, b3.w};
        const float4* cr = (const float4*)&CL[i * NN];
        float4 c0 = cr[0], c1 = cr[1], c2 = cr[2], c3 = cr[3];
        float Cv[16] = {c0.x, c0.y, c0.z, c0.w, c1.x, c1.y, c1.z, c1.w,
                        c2.x, c2.y, c2.z, c2.w, c3.x, c3.y, c3.z, c3.w};
        float y = 0.0f;
#pragma unroll
        for (int n = 0; n < NN; ++n) {
            float dA = exp2f(sp_[i] * A2[n]);
            h[n] = fmaf(dA, h[n], du * Bv[n]);
            y = fmaf(h[n], Cv[n], y);
        }
        y = fmaf(dval, uvv[i], y);
        yp[(size_t)(lt0 + i) * NCH] = y;
    }
    size_t ob = (((size_t)bk * NCHUNK + chk) * NCH + c) * NN;
#pragma unroll
    for (int q = 0; q < 4; ++q)
        *(float4*)&Hend[ob + q * 4] =
            make_float4(h[q*4], h[q*4+1], h[q*4+2], h[q*4+3]);
}

// ------------- scan pass 2: parallel chunk prefix (Hillis-Steele in LDS).
// One block per (bk,c): thread j owns chunk j's (P,E) pair (16 n in regs).
// After this kernel Hend[j] holds the INCOMING state for chunk j.
#define SP2 17
__global__ __launch_bounds__(192) void k_s2(const float* __restrict__ cumS,
                                            const float* __restrict__ A2buf,
                                            float* __restrict__ Hend) {
    __shared__ float LP[NCHUNK * SP2];   // pad 17 -> conflict-free stride
    __shared__ float LE[NCHUNK * SP2];
    int bid = blockIdx.x;                // 8 * 192
    int bk = bid / NCH, c = bid % NCH;
    int k = bk & 3;
    int j = threadIdx.x;                 // chunk index (j < 144 active)
    float A2[NN], P[NN], E[NN];
    size_t eb = 0;
    if (j < NCHUNK) {
        const float4* ap = (const float4*)(A2buf + ((size_t)(k * NCH + c)) * NN);
        float4 a0 = ap[0], a1 = ap[1], a2 = ap[2], a3 = ap[3];
        float t[16] = {a0.x, a0.y, a0.z, a0.w, a1.x, a1.y, a1.z, a1.w,
                       a2.x, a2.y, a2.z, a2.w, a3.x, a3.y, a3.z, a3.w};
#pragma unroll
        for (int n = 0; n < NN; ++n) A2[n] = t[n];
        float Sv = cumS[(size_t)bk * NL * NCH + (size_t)(j * CLEN + CLEN - 1) * NCH + c];
        eb = (((size_t)bk * NCHUNK + j) * NCH + c) * NN;
        const float4* hp = (const float4*)(Hend + eb);
        float4 e0 = hp[0], e1 = hp[1], e2 = hp[2], e3 = hp[3];
        float te[16] = {e0.x, e0.y, e0.z, e0.w, e1.x, e1.y, e1.z, e1.w,
                        e2.x, e2.y, e2.z, e2.w, e3.x, e3.y, e3.z, e3.w};
#pragma unroll
        for (int n = 0; n < NN; ++n) {
            E[n] = te[n];
            P[n] = exp2f(Sv * A2[n]);
            LP[j * SP2 + n] = P[n];
            LE[j * SP2 + n] = E[n];
        }
    }
    for (int s = 1; s < NCHUNK; s <<= 1) {   // 8 steps
        __syncthreads();
        float pe[NN], ee[NN];
        bool act = (j < NCHUNK) && (j >= s);
        if (act) {
#pragma unroll
            for (int n = 0; n < NN; ++n) {
                pe[n] = LP[(j - s) * SP2 + n];
                ee[n] = LE[(j - s) * SP2 + n];
            }
        }
        __syncthreads();
        if (act) {
#pragma unroll
            for (int n = 0; n < NN; ++n) {
                E[n] = fmaf(P[n], ee[n], E[n]);   // E = P_cur*E_left + E_cur
                P[n] = P[n] * pe[n];
                LP[j * SP2 + n] = P[n];
                LE[j * SP2 + n] = E[n];
            }
        }
    }
    __syncthreads();
    if (j < NCHUNK) {
        float o[NN];
        if (j == 0) {
#pragma unroll
            for (int n = 0; n < NN; ++n) o[n] = 0.0f;
        } else {
#pragma unroll
            for (int n = 0; n < NN; ++n) o[n] = LE[(j - 1) * SP2 + n];
        }
#pragma unroll
        for (int qq = 0; qq < 4; ++qq)
            *(float4*)&Hend[eb + qq * 4] =
                make_float4(o[qq*4], o[qq*4+1], o[qq*4+2], o[qq*4+3]);
    }
}

// -------- fix: y += C · (exp2(cumS·A2) ∘ h_in) — split into 8-l half-chunks
__global__ __launch_bounds__(192) void k_fix(const float* __restrict__ Cbuf,
                                             const float* __restrict__ cumS,
                                             const float* __restrict__ Hin,
                                             const float* __restrict__ A2buf,
                                             float* __restrict__ ybuf) {
    int bid = blockIdx.x;                      // 8 * 288
    int bk = bid / (NLT * 2);
    int r = bid % (NLT * 2);
    int chk = r >> 1, hf = r & 1;
    int lt0 = chk * LTILE + hf * 8;
    int k = bk & 3;
    int c = threadIdx.x;
    float A2[NN];
    {
        const float4* ap = (const float4*)(A2buf + ((size_t)(k * NCH + c)) * NN);
        float4 a0 = ap[0], a1 = ap[1], a2 = ap[2], a3 = ap[3];
        A2[0]=a0.x; A2[1]=a0.y; A2[2]=a0.z; A2[3]=a0.w;
        A2[4]=a1.x; A2[5]=a1.y; A2[6]=a1.z; A2[7]=a1.w;
        A2[8]=a2.x; A2[9]=a2.y; A2[10]=a2.z; A2[11]=a2.w;
        A2[12]=a3.x; A2[13]=a3.y; A2[14]=a3.z; A2[15]=a3.w;
    }
    float hin[NN];
    {
        size_t ob = (((size_t)bk * NCHUNK + chk) * NCH + c) * NN;
        const float4* hp = (const float4*)(Hin + ob);
        float4 h0 = hp[0], h1 = hp[1], h2 = hp[2], h3 = hp[3];
        float t[16] = {h0.x, h0.y, h0.z, h0.w, h1.x, h1.y, h1.z, h1.w,
                       h2.x, h2.y, h2.z, h2.w, h3.x, h3.y, h3.z, h3.w};
#pragma unroll
        for (int n = 0; n < NN; ++n) hin[n] = t[n];
    }
    const float* csp = cumS + (size_t)bk * NL * NCH + c;
    float* yp = ybuf + (size_t)bk * NL * NCH + c;
#pragma unroll
    for (int i = 0; i < 8; ++i) {
        int l = lt0 + i;
        float cs = csp[(size_t)l * NCH];
        const float4* cr = (const float4*)(Cbuf + ((size_t)bk * NL + l) * NN);
        float4 c0 = cr[0], c1 = cr[1], c2 = cr[2], c3 = cr[3];
        float Cv[16] = {c0.x, c0.y, c0.z, c0.w, c1.x, c1.y, c1.z, c1.w,
                        c2.x, c2.y, c2.z, c2.w, c3.x, c3.y, c3.z, c3.w};
        float corr = 0.0f;
#pragma unroll
        for (int n = 0; n < NN; ++n) {
            float e = exp2f(cs * A2[n]);
            corr = fmaf(Cv[n] * hin[n], e, corr);
        }
        yp[(size_t)l * NCH] += corr;
    }
}

// ------------------------------------------- cross-merge, split ×4 over c
__global__ __launch_bounds__(256) void k_merge(const float* __restrict__ ybuf,
                                               float* __restrict__ out) {
    int bid = blockIdx.x;                // NB * NH * 4 = 384
    int b = bid / (NH * 4);
    int r = bid % (NH * 4);
    int hh = r >> 2, cq = r & 3;
    int cbase = cq * 48;
    __shared__ float tile[NW * 49];
    const float* Y0 = ybuf + (size_t)(b * NK + 0) * NL * NCH;
    const float* Y1 = ybuf + (size_t)(b * NK + 1) * NL * NCH;
    const float* Y2 = ybuf + (size_t)(b * NK + 2) * NL * NCH;
    const float* Y3 = ybuf + (size_t)(b * NK + 3) * NL * NCH;
    for (int i = threadIdx.x; i < NW * 48; i += 256) {
        int w = i / 48, cs = i % 48;
        int c = cbase + cs;
        int hw = hh * NW + w;
        int wh = w * NH + hh;
        float v = Y0[(size_t)hw * NCH + c]
                + Y2[(size_t)(NL - 1 - hw) * NCH + c]
                + Y1[(size_t)wh * NCH + c]
                + Y3[(size_t)(NL - 1 - wh) * NCH + c];
        tile[w * 49 + cs] = v;
    }
    __syncthreads();
    for (int i = threadIdx.x; i < NW * 48; i += 256) {
        int cs = i / NW, w = i % NW;
        out[((size_t)(b * NCH + cbase + cs)) * NL + hh * NW + w] = tile[w * 49 + cs];
    }
}

extern "C" void kernel_launch(void* const* d_in, const int* in_sizes, int n_in,
                              void* d_out, int out_size, void* d_ws, size_t ws_size,
                              hipStream_t stream) {
    const float* x      = (const float*)d_in[0];
    const float* xpw    = (const float*)d_in[1];
    const float* dtw    = (const float*)d_in[2];
    const float* A_logs = (const float*)d_in[3];
    const float* Ds     = (const float*)d_in[4];
    const float* dtb    = (const float*)d_in[5];
    float* out = (float*)d_out;

    float* ws = (float*)d_ws;
    float* xT    = ws;
    float* ut0   = xT + SZ_XT;
    float* Cbuf  = ut0 + SZ_UT0;
    float* cumS  = Cbuf + SZ_CB;
    float* ybuf  = cumS + SZ_CUMS;
    float* Hend  = ybuf + SZ_YBUF;   // after k_s2 holds Hin (in-place)
    float* A2buf = Hend + SZ_HEND;
    float* xpwT  = A2buf + SZ_A2;

    k_prep<<<NB * NCH + NB * 36 + 12 + NK, 256, 0, stream>>>(x, A_logs, xpw,
                                                             xT, ut0, A2buf, xpwT);
    k_projscan<<<NB * NK * NLT, 192, 0, stream>>>(x, xT, xpwT, dtw, dtb, A2buf,
                                                  Ds, ut0, Cbuf, cumS, ybuf, Hend);
    k_s2<<<NB * NK * NCH, 192, 0, stream>>>(cumS, A2buf, Hend);
    k_fix<<<NB * NK * NLT * 2, 192, 0, stream>>>(Cbuf, cumS, Hend, A2buf, ybuf);
    k_merge<<<NB * NH * 4, 256, 0, stream>>>(ybuf, out);
}